// Round 3
// baseline (10712.413 us; speedup 1.0000x reference)
//
#include <hip/hip_runtime.h>

// Problem dims
constexpr int kB    = 64;
constexpr int kT    = 512;
constexpr int kDin  = 256;
constexpr int kH    = 1024;
constexpr int kH3   = 3072;
constexpr int kDout = 256;
constexpr int kWR   = kH / 2;     // tagged 8B words per h row (2 bf16 each)
constexpr int kHS   = kB * kWR;   // words per parity buffer

typedef float  f32x4  __attribute__((ext_vector_type(4)));
typedef __bf16 bf16x8 __attribute__((ext_vector_type(8)));
typedef unsigned u32x4 __attribute__((ext_vector_type(4)));
typedef unsigned long long u64;

__device__ __forceinline__ float b2f(unsigned short u) {
  union { float f; unsigned u32; } c; c.u32 = ((unsigned)u) << 16; return c.f;
}
__device__ __forceinline__ unsigned short f2b(float f) {
  union { float f; unsigned u32; } c; c.f = f;
  unsigned r = c.u32 + 0x7fffu + ((c.u32 >> 16) & 1u);  // RNE
  return (unsigned short)(r >> 16);
}
__device__ __forceinline__ bf16x8 ld8(const unsigned short* p) {
  return *reinterpret_cast<const bf16x8*>(p);
}
__device__ __forceinline__ u64 ald(const u64* p) {
  return __hip_atomic_load(p, __ATOMIC_RELAXED, __HIP_MEMORY_SCOPE_AGENT);
}
__device__ __forceinline__ void ast(u64* p, u64 v) {
  __hip_atomic_store(p, v, __ATOMIC_RELAXED, __HIP_MEMORY_SCOPE_AGENT);
}
__device__ __forceinline__ float sigm_(float x) { return 1.f / (1.f + __expf(-x)); }
__device__ __forceinline__ float tanh_(float x) {
  return 1.f - 2.f / (__expf(2.f * x) + 1.f);
}

#define MFMA16(a, b, c) __builtin_amdgcn_mfma_f32_16x16x32_bf16((a), (b), (c), 0, 0, 0)

// ---------------------------------------------------------------------------
// Prep: fp32->bf16 conversion, combined biases, tagged h-buffer init.
// Tag scheme: h_[s] stored with tag s+2. Initial h_[-1] = parity 1, tag 1;
// parity 0 gets tag 0 (never matches a poll before its first real write).
// ---------------------------------------------------------------------------
__global__ void gru_prep(const float* __restrict__ x,
                         const float* __restrict__ Wi0, const float* __restrict__ Wh0,
                         const float* __restrict__ bi0, const float* __restrict__ bh0,
                         const float* __restrict__ Wi1, const float* __restrict__ Wh1,
                         const float* __restrict__ bi1, const float* __restrict__ bh1,
                         unsigned short* __restrict__ xb,
                         unsigned short* __restrict__ wi0b, unsigned short* __restrict__ wh0b,
                         unsigned short* __restrict__ wi1b, unsigned short* __restrict__ wh1b,
                         u64* __restrict__ h0t, u64* __restrict__ h1t,
                         float* __restrict__ bias) {
  const int stride = gridDim.x * blockDim.x;
  const int g = blockIdx.x * blockDim.x + threadIdx.x;
  for (int i = g; i < kH3 * kDin; i += stride) wi0b[i] = f2b(Wi0[i]);
  for (int i = g; i < kH3 * kH; i += stride) {
    wh0b[i] = f2b(Wh0[i]); wi1b[i] = f2b(Wi1[i]); wh1b[i] = f2b(Wh1[i]);
  }
  for (int i = g; i < kB * kT * kDin; i += stride) xb[i] = f2b(x[i]);
  for (int i = g; i < kHS; i += stride) {
    h0t[i] = 0;                      // parity 0: tag 0, data 0
    h1t[i] = 0;
    h0t[kHS + i] = (u64)1 << 32;     // parity 1 (= h[-1]): tag 1, data 0
    h1t[kHS + i] = (u64)1 << 32;
  }
  for (int i = g; i < kH; i += stride) {
    bias[0 * kH + i] = bi0[0 * kH + i] + bh0[0 * kH + i];
    bias[1 * kH + i] = bi0[1 * kH + i] + bh0[1 * kH + i];
    bias[2 * kH + i] = bi0[2 * kH + i];
    bias[3 * kH + i] = bh0[2 * kH + i];
    bias[4 * kH + i] = bi1[0 * kH + i] + bh1[0 * kH + i];
    bias[5 * kH + i] = bi1[1 * kH + i] + bh1[1 * kH + i];
    bias[6 * kH + i] = bi1[2 * kH + i];
    bias[7 * kH + i] = bh1[2 * kH + i];
  }
}

// ---------------------------------------------------------------------------
// Persistent pipelined GRU, barrier-free. Grid 256 x 512.
// Waves 0-3: layer0 tick t; waves 4-7: layer1 tick t-1.
// h words carry tick tags; consumers poll data directly (1 IF round trip).
// L0 loads h0[t-1] fragments once and shares them with L1 via LDS.
// ---------------------------------------------------------------------------
__global__ void __launch_bounds__(512, 2) gru_main(
    const unsigned short* __restrict__ xb,
    const unsigned short* __restrict__ wi0, const unsigned short* __restrict__ wh0,
    const unsigned short* __restrict__ wi1, const unsigned short* __restrict__ wh1,
    const float* __restrict__ bias,
    u64* __restrict__ h0t, u64* __restrict__ h1t,
    const float* __restrict__ Wo, const float* __restrict__ bo,
    float* __restrict__ out) {
  __shared__ u32x4 h0sh[4][8][64];       // h0[t-1] A-frags: [kw][ks][lane]
  __shared__ float red[2][4][4][64][5];  // [layer][kw][gate][lane][reg(+pad)]

  const int tid   = threadIdx.x;
  const int lane  = tid & 63;
  const int wv    = tid >> 6;
  const int layer = wv >> 2;
  const int kw    = wv & 3;

  const int xcd  = blockIdx.x & 7;       // weight-slice XCD affinity
  const int slot = blockIdx.x >> 3;
  const int mt   = slot & 3;
  const int jt   = (slot >> 2) * 8 + xcd;

  const int ln15 = lane & 15;
  const int quad = lane >> 4;
  const int bA   = mt * 16 + ln15;       // A-frag batch row
  const int jr   = jt * 16 + ln15;       // B-frag hidden-unit row
  const int jg   = jt * 16 + ln15;       // C/D col
  const int bg   = mt * 16 + quad * 4 + kw;  // C/D row this thread reduces

  const unsigned short* whb = (layer == 0) ? wh0 : wh1;
  const unsigned short* wib = (layer == 0) ? wi0 : wi1;
  const int wiK = (layer == 0) ? kDin : kH;
  const unsigned short* wh_r = whb + (size_t)(0 * kH + jr) * kH + kw * 256 + quad * 8;
  const unsigned short* wh_z = whb + (size_t)(1 * kH + jr) * kH + kw * 256 + quad * 8;
  const unsigned short* wh_n = whb + (size_t)(2 * kH + jr) * kH + kw * 256 + quad * 8;
  const unsigned short* wi_r = wib + (size_t)(0 * kH + jr) * wiK + kw * ((layer == 0) ? 64 : 256) + quad * 8;
  const unsigned short* wi_z = wib + (size_t)(1 * kH + jr) * wiK + kw * ((layer == 0) ? 64 : 256) + quad * 8;
  const unsigned short* wi_n = wib + (size_t)(2 * kH + jr) * wiK + kw * ((layer == 0) ? 64 : 256) + quad * 8;

  const f32x4 z4 = {0.f, 0.f, 0.f, 0.f};

  for (int t = 0; t <= kT; ++t) {
    const int p0r = (t + 1) & 1, p0w = t & 1;        // h0: read t-1, write t
    const int p1r = t & 1,       p1w = (t + 1) & 1;  // h1: read t-2, write t-1
    const bool l0c = (t < kT);
    const bool l1c = (t >= 1);

    f32x4 ar = z4, az = z4, ai = z4, ah = z4;
    bf16x8 hfr[8];
    bf16x8 xf0 = {}, xf1 = {};
    float hp = 0.f;

    // ---------------- phase A: batched poll loads --------------------------
    if (layer == 0) {
      if (l0c) {  // x fragment prefetch (plain cached, overlaps poll)
        const unsigned short* xp =
            xb + (size_t)bA * (kT * kDin) + t * kDin + kw * 64 + quad * 8;
        xf0 = ld8(xp); xf1 = ld8(xp + 32);
      }
      // poll h0[t-1] (tag t+1): always, incl. t==kT (L1 needs the LDS copy)
      const u64* ap  = h0t + (size_t)p0r * kHS + (size_t)bA * kWR + kw * 128 + quad * 4;
      const u64* hpp = h0t + (size_t)p0r * kHS + (size_t)bg * kWR + (jg >> 1);
      const unsigned want = (unsigned)(t + 1);
      u64 w[32], wx;
      for (;;) {
#pragma unroll
        for (int ks = 0; ks < 8; ++ks)
#pragma unroll
          for (int q = 0; q < 4; ++q) w[ks * 4 + q] = ald(ap + ks * 16 + q);
        wx = ald(hpp);
        bool ok = ((unsigned)(wx >> 32)) == want;
#pragma unroll
        for (int i = 0; i < 32; ++i) ok &= ((unsigned)(w[i] >> 32)) == want;
        if (__all(ok)) break;
        __builtin_amdgcn_s_sleep(4);
      }
      hp = b2f((unsigned short)((jg & 1) ? ((unsigned)wx) >> 16
                                         : ((unsigned)wx) & 0xffff));
#pragma unroll
      for (int ks = 0; ks < 8; ++ks) {
        union { u32x4 u4; unsigned u[4]; bf16x8 v; } c;
#pragma unroll
        for (int q = 0; q < 4; ++q) c.u[q] = (unsigned)w[ks * 4 + q];
        hfr[ks] = c.v;
        h0sh[kw][ks][lane] = c.u4;
      }
    } else if (l1c) {
      // poll h1[t-2] (tag t)
      const u64* ap  = h1t + (size_t)p1r * kHS + (size_t)bA * kWR + kw * 128 + quad * 4;
      const u64* hpp = h1t + (size_t)p1r * kHS + (size_t)bg * kWR + (jg >> 1);
      const unsigned want = (unsigned)t;
      u64 w[32], wx;
      for (;;) {
#pragma unroll
        for (int ks = 0; ks < 8; ++ks)
#pragma unroll
          for (int q = 0; q < 4; ++q) w[ks * 4 + q] = ald(ap + ks * 16 + q);
        wx = ald(hpp);
        bool ok = ((unsigned)(wx >> 32)) == want;
#pragma unroll
        for (int i = 0; i < 32; ++i) ok &= ((unsigned)(w[i] >> 32)) == want;
        if (__all(ok)) break;
        __builtin_amdgcn_s_sleep(4);
      }
      hp = b2f((unsigned short)((jg & 1) ? ((unsigned)wx) >> 16
                                         : ((unsigned)wx) & 0xffff));
#pragma unroll
      for (int ks = 0; ks < 8; ++ks) {
        union { unsigned u[4]; bf16x8 v; } c;
#pragma unroll
        for (int q = 0; q < 4; ++q) c.u[q] = (unsigned)w[ks * 4 + q];
        hfr[ks] = c.v;
      }
    }
    __syncthreads();  // h0sh ready; also closes last tick's red reads

    // ---------------- phase B: MFMA ----------------------------------------
    if (layer == 0) {
      if (l0c) {
#pragma unroll
        for (int ks = 0; ks < 8; ++ks) {
          ar = MFMA16(hfr[ks], ld8(wh_r + ks * 32), ar);
          az = MFMA16(hfr[ks], ld8(wh_z + ks * 32), az);
          ah = MFMA16(hfr[ks], ld8(wh_n + ks * 32), ah);
        }
        ar = MFMA16(xf0, ld8(wi_r), ar);
        az = MFMA16(xf0, ld8(wi_z), az);
        ai = MFMA16(xf0, ld8(wi_n), ai);
        ar = MFMA16(xf1, ld8(wi_r + 32), ar);
        az = MFMA16(xf1, ld8(wi_z + 32), az);
        ai = MFMA16(xf1, ld8(wi_n + 32), ai);
      }
    } else if (l1c) {
#pragma unroll
      for (int ks = 0; ks < 8; ++ks) {
        union { u32x4 u4; bf16x8 v; } c;
        c.u4 = h0sh[kw][ks][lane];
        ar = MFMA16(c.v, ld8(wi_r + ks * 32), ar);
        az = MFMA16(c.v, ld8(wi_z + ks * 32), az);
        ai = MFMA16(c.v, ld8(wi_n + ks * 32), ai);
        ar = MFMA16(hfr[ks], ld8(wh_r + ks * 32), ar);
        az = MFMA16(hfr[ks], ld8(wh_z + ks * 32), az);
        ah = MFMA16(hfr[ks], ld8(wh_n + ks * 32), ah);
      }
    }

    // ---------------- phase C: K-reduce + gates + tagged store -------------
#pragma unroll
    for (int q = 0; q < 4; ++q) {
      red[layer][kw][0][lane][q] = ar[q]; red[layer][kw][1][lane][q] = az[q];
      red[layer][kw][2][lane][q] = ai[q]; red[layer][kw][3][lane][q] = ah[q];
    }
    __syncthreads();

    const bool act = (layer == 0) ? l0c : l1c;
    if (act) {
      float sr = 0, sz = 0, si = 0, sh = 0;
#pragma unroll
      for (int w = 0; w < 4; ++w) {
        sr += red[layer][w][0][lane][kw]; sz += red[layer][w][1][lane][kw];
        si += red[layer][w][2][lane][kw]; sh += red[layer][w][3][lane][kw];
      }
      const float* bb = bias + layer * 4 * kH;
      float rg = sigm_(sr + bb[jg]);
      float zg = sigm_(sz + bb[kH + jg]);
      float ng = tanh_(si + bb[2 * kH + jg] + rg * (sh + bb[3 * kH + jg]));
      float hv = (1.f - zg) * ng + zg * hp;
      float pv = __shfl_xor(hv, 1);
      if (!(ln15 & 1)) {
        unsigned pk = (unsigned)f2b(hv) | ((unsigned)f2b(pv) << 16);
        u64* dst = ((layer == 0) ? h0t + (size_t)p0w * kHS
                                 : h1t + (size_t)p1w * kHS) +
                   (size_t)bg * kWR + (jg >> 1);
        const unsigned tag = (layer == 0) ? (unsigned)(t + 2) : (unsigned)(t + 1);
        ast(dst, (u64)pk | ((u64)tag << 32));
      }
    }
  }

  // ---------------- output projection (poll tags, no barrier) --------------
  // h1[511]: parity 1, tag 513. Block (jt,mt) -> row r, 64-col segment.
  {
    const int r  = mt * 16 + (jt >> 2);
    const int c0 = (jt & 3) * 64;
    const int o  = tid >> 3;       // 0..63
    const int ks = tid & 7;        // k segment 0..7 (128 k each)
    const u64* hrow = h1t + (size_t)1 * kHS + (size_t)r * kWR + ks * 64;
    const float* wrow = Wo + (size_t)(c0 + o) * kH + ks * 128;
    float acc = 0.f;
#pragma unroll
    for (int c = 0; c < 8; ++c) {
      u64 w8[8];
      for (;;) {
#pragma unroll
        for (int q = 0; q < 8; ++q) w8[q] = ald(hrow + c * 8 + q);
        bool ok = true;
#pragma unroll
        for (int q = 0; q < 8; ++q) ok &= ((unsigned)(w8[q] >> 32)) == 513u;
        if (__all(ok)) break;
        __builtin_amdgcn_s_sleep(4);
      }
#pragma unroll
      for (int q = 0; q < 8; ++q) {
        unsigned d = (unsigned)w8[q];
        acc += b2f((unsigned short)(d & 0xffff)) * wrow[c * 16 + q * 2] +
               b2f((unsigned short)(d >> 16))    * wrow[c * 16 + q * 2 + 1];
      }
    }
    acc += __shfl_xor(acc, 1);
    acc += __shfl_xor(acc, 2);
    acc += __shfl_xor(acc, 4);
    if (ks == 0) out[r * kDout + c0 + o] = acc + bo[c0 + o];
  }
}

// ---------------------------------------------------------------------------
extern "C" void kernel_launch(void* const* d_in, const int* in_sizes, int n_in,
                              void* d_out, int out_size, void* d_ws, size_t ws_size,
                              hipStream_t stream) {
  const float* x   = (const float*)d_in[0];
  const float* Wi0 = (const float*)d_in[1];
  const float* Wh0 = (const float*)d_in[2];
  const float* bi0 = (const float*)d_in[3];
  const float* bh0 = (const float*)d_in[4];
  const float* Wi1 = (const float*)d_in[5];
  const float* Wh1 = (const float*)d_in[6];
  const float* bi1 = (const float*)d_in[7];
  const float* bh1 = (const float*)d_in[8];
  const float* Wo  = (const float*)d_in[9];
  const float* bo  = (const float*)d_in[10];

  char* ws = (char*)d_ws;
  size_t off = 0;
  auto take = [&](size_t bytes) {
    size_t r = off;
    off += (bytes + 255) & ~(size_t)255;
    return r;
  };
  unsigned short* xb   = (unsigned short*)(ws + take((size_t)kB * kT * kDin * 2));
  unsigned short* wi0b = (unsigned short*)(ws + take((size_t)kH3 * kDin * 2));
  unsigned short* wh0b = (unsigned short*)(ws + take((size_t)kH3 * kH * 2));
  unsigned short* wi1b = (unsigned short*)(ws + take((size_t)kH3 * kH * 2));
  unsigned short* wh1b = (unsigned short*)(ws + take((size_t)kH3 * kH * 2));
  u64*            h0t  = (u64*)(ws + take((size_t)2 * kHS * 8));
  u64*            h1t  = (u64*)(ws + take((size_t)2 * kHS * 8));
  float*          bias = (float*)(ws + take(8 * kH * sizeof(float)));

  gru_prep<<<2048, 256, 0, stream>>>(x, Wi0, Wh0, bi0, bh0, Wi1, Wh1, bi1, bh1,
                                     xb, wi0b, wh0b, wi1b, wh1b, h0t, h1t, bias);
  gru_main<<<256, 512, 0, stream>>>(xb, wi0b, wh0b, wi1b, wh1b, bias, h0t, h1t,
                                    Wo, bo, (float*)d_out);
}